// Round 1
// baseline (240.549 us; speedup 1.0000x reference)
//
#include <hip/hip_runtime.h>
#include <hip/hip_bf16.h>

#define DIM 256
#define HW  1024  // 32*32

typedef __attribute__((ext_vector_type(8))) short short8;
typedef __attribute__((ext_vector_type(4))) float floatx4;
typedef __attribute__((ext_vector_type(16))) float floatx16;
typedef __attribute__((address_space(1))) const unsigned int g_u32;
typedef __attribute__((address_space(3))) unsigned int l_u32;

// softmax scale folded into Q at conv epilogue: 0.25 * log2(e)
#define QSCALE 0.36067376022224085f

__device__ inline unsigned short f2bf(float f) {
  union { float f; unsigned u; } v;
  v.f = f;
  unsigned u = v.u;
  u += 0x7fffu + ((u >> 16) & 1u);
  return (unsigned short)(u >> 16);
}

__device__ inline unsigned short f2bf_trunc(float f) {  // RTZ: 1 VALU inst
  union { float f; unsigned u; } v;
  v.f = f;
  return (unsigned short)(v.u >> 16);
}

__device__ inline float ldin(const void* p, long i, int isf32) {
  if (isf32) return ((const float*)p)[i];
  union { unsigned u; float f; } v;
  v.u = ((unsigned)((const unsigned short*)p)[i]) << 16;
  return v.f;
}

// ---------------------------------------------------------------------------
// R21 fused prep (unchanged).
// wF layout (unchanged): [tap][c8(8)][co16(16)][lane(64)][j(8)],
//   co = co16*16 + (lane&15), ci = c8*32 + (lane>>4)*8 + j.
// ---------------------------------------------------------------------------
__device__ inline int detect_inline(const unsigned short* __restrict__ xr,
                                    int* cnt) {
  if (threadIdx.x == 0) *cnt = 0;
  __syncthreads();
  int local = 0;
  for (int i = threadIdx.x; i < 8192; i += 256) {
    unsigned short u = xr[i];
    if ((u & 0x7F80u) == 0x7F80u) local++;
  }
  if (local) atomicAdd(cnt, local);
  __syncthreads();
  return (*cnt > 0) ? 1 : 0;
}

__device__ inline void frag_repack4(const void* __restrict__ w,
                                    unsigned short* __restrict__ wF, int KK,
                                    int slice, float* __restrict__ Wl,
                                    int isf32) {
  const int t = threadIdx.x;
  const int co16 = slice & 15;
  const int c8   = slice >> 4;
  const int RE = 32 * KK;   // elems per co row (contiguous in source)
  const int RS = RE + 1;    // padded LDS row stride (801 max == 1 mod 32)
  for (int g = 0; g < 4; ++g) {       // 4 co rows per pass
    __syncthreads();                  // previous pass's reads done
    for (int rloc = 0; rloc < 4; ++rloc) {
      const long base =
          ((long)((co16 * 16 + (g << 2) + rloc) * 256 + c8 * 32)) * KK;
      for (int i = t; i < RE; i += 256)
        Wl[rloc * RS + i] = ldin(w, base + i, isf32);
    }
    __syncthreads();
    for (int tap = 0; tap < KK; ++tap) {
      unsigned short* dst = wF + ((((tap << 3) + c8) << 4) + co16) * 512;
      if (t < 128) {
        const int colg = t >> 5;          // local co row 0..3
        const int cis  = t & 31;          // ci-sub 0..31
        const int col  = (g << 2) + colg; // co within co16 tile
        const int lane = ((cis >> 3) << 4) | col;
        const int j    = cis & 7;
        dst[lane * 8 + j] = f2bf(Wl[colg * RS + cis * KK + tap]);
      }
    }
  }
}

__global__ __launch_bounds__(256) void prep_kernel(
    const void* __restrict__ x,  const void* __restrict__ w3,
    const void* __restrict__ b3, const void* __restrict__ w5,
    const void* __restrict__ b5, const void* __restrict__ w7,
    const void* __restrict__ b7, const void* __restrict__ wp,
    unsigned short* __restrict__ xbf,
    unsigned short* __restrict__ wF3, unsigned short* __restrict__ wF5,
    unsigned short* __restrict__ wF7, unsigned short* __restrict__ wpF,
    float* __restrict__ bc, int* __restrict__ flag) {
  __shared__ float Wl[4 * 801];  // 12.8 KB
  __shared__ int cnt;
  const int isf32 = detect_inline((const unsigned short*)x, &cnt);
  const int bid = blockIdx.x;
  const int t = threadIdx.x;
  if (bid < 512) {  // xconv: 16 elems/thread, 4 coalesced rounds
#pragma unroll
    for (int r = 0; r < 4; ++r) {
      const int i = (bid * 1024 + r * 256 + t) * 4;
      if (isf32) {
        const float4 v = *(const float4*)((const float*)x + i);
        ushort4 o;
        o.x = f2bf(v.x); o.y = f2bf(v.y); o.z = f2bf(v.z); o.w = f2bf(v.w);
        *(ushort4*)(xbf + i) = o;
      } else {
        *(ushort4*)(xbf + i) =
            *(const ushort4*)((const unsigned short*)x + i);
      }
    }
  } else if (bid < 640) {
    frag_repack4(w7, wF7, 25, bid - 512, Wl, isf32);
  } else if (bid < 768) {
    frag_repack4(w5, wF5, 9, bid - 640, Wl, isf32);
  } else if (bid < 896) {
    frag_repack4(w3, wF3, 1, bid - 768, Wl, isf32);
  } else if (bid < 1024) {
    frag_repack4(wp, wpF, 1, bid - 896, Wl, isf32);
  } else {  // biases (q=b3, v=b5, k=b7) + publish flag
#pragma unroll
    for (int r = 0; r < 3; ++r) {
      const int i = r * 256 + t;
      const void* src = (i < 256) ? b3 : (i < 512) ? b5 : b7;
      bc[i] = ldin(src, i & 255, isf32);
    }
    if (t == 0) *flag = isf32;
  }
}

// ---------------------------------------------------------------------------
// R22 conv: LDS-roofline rebalance.
//  - co-tile per block 16 -> 32 (two co16 frags per wave): X-LDS bytes per
//    MFMA halve (was the dominant port at ~95% busy, 2.4:1 vs MFMA).
//  - B operands direct global->VGPR (fragment layout is a coalesced 1KB
//    wave-load): moves B traffic to the L1 port, deletes Bs LDS + the
//    global_load_lds vmcnt(0) barrier drain.
//  - grid 256 = 32 m-groups x 8 co-pairs, 1 block/CU, LDS = Xs only 34.6KB.
//  - X staging + attention coords byte-identical to R17/R19-verified code.
// Attention coords (R2/R11-verified): slab=(b<<4)+(co>>4), m=(co&15)*64+(n>>4),
//   d=n&15;  q/k rows: (slab<<14)+((co&15)<<10)+n ;  v (V^T):
//   (slab<<14)+((n&15)<<10)+((co&15)<<6)+(n>>4)
// ---------------------------------------------------------------------------
__global__ __launch_bounds__(256, 1) void convqkv_kernel(
    const unsigned short* __restrict__ xbf,
    const unsigned short* __restrict__ wFq,  // 1 tap
    const unsigned short* __restrict__ wFv,  // 9 taps
    const unsigned short* __restrict__ wFk,  // 25 taps
    const float* __restrict__ bc,            // [3][256] q,v,k
    unsigned short* __restrict__ qOut,
    unsigned short* __restrict__ vOut,
    unsigned short* __restrict__ kOut) {
  constexpr int WC = 36;            // halo cols (32 + 2*2)
  constexpr int CELLS = 12 * WC;    // 12 halo rows = 432 cells
  constexpr int LOADS = CELLS * 4;  // 1728 halo dwordx4 loads
  __shared__ unsigned short Xs[CELLS * 40];  // halo [cell][32ci pad40] 34.6KB
  const int t    = threadIdx.x;
  const int bid  = blockIdx.x;         // 256 = 32 m-groups x 8 co-pairs
  const int cp   = bid & 7;
  const int cog0 = cp << 1;            // first co16 group of the pair
  const int co0  = cp << 5;            // 32 co per block
  const int m0   = (bid >> 3) << 8;    // 256 positions (8 image rows)
  const int b    = m0 >> 10;
  const int n0   = m0 & 1023;
  const int r0   = n0 >> 5;
  const int wv   = t >> 6;
  const int lane = t & 63;
  const int l15  = lane & 15;
  const int quad = lane >> 4;

  floatx4 aq[4][2] = {}, av[4][2] = {}, ak[4][2] = {};

  for (int c8 = 0; c8 < 8; ++c8) {
    uint4 xreg[7];
#pragma unroll
    for (int rr = 0; rr < 7; ++rr) {
      const int id = rr * 256 + t;
      const int cell = id >> 2, part = id & 3;
      const int hr = cell / WC, wc = cell - hr * WC;
      const int xr = r0 + hr - 2, xc = wc - 2;
      const bool ok = (id < LOADS) && ((unsigned)xr < 32u) &&
                      ((unsigned)xc < 32u);
      const int cr = xr < 0 ? 0 : (xr > 31 ? 31 : xr);
      const int cc = xc < 0 ? 0 : (xc > 31 ? 31 : xc);
      uint4 v = *(const uint4*)&xbf[(((b * 32 + cr) * 32 + cc) << 8) +
                                    (c8 << 5) + (part << 3)];
      if (!ok) v = make_uint4(0, 0, 0, 0);
      xreg[rr] = v;
    }
    __syncthreads();
#pragma unroll
    for (int rr = 0; rr < 7; ++rr) {
      const int id = rr * 256 + t;
      if (id < LOADS)
        *(uint4*)&Xs[(id >> 2) * 40 + ((id & 3) << 3)] = xreg[rr];
    }
    __syncthreads();

#pragma unroll
    for (int tap = 0; tap < 25; ++tap) {
      const int kh = tap / 5, kw = tap % 5;
      const bool vv = (kh >= 1 && kh <= 3 && kw >= 1 && kw <= 3);
      short8 a[4];
#pragma unroll
      for (int rr2 = 0; rr2 < 2; ++rr2) {
#pragma unroll
        for (int ch = 0; ch < 2; ++ch) {
          const unsigned short* xs =
              &Xs[(((wv << 1) + rr2 + kh) * WC + (ch << 4) + l15 + kw) * 40 +
                  (quad << 3)];
          a[(rr2 << 1) + ch] = *(const short8*)xs;
        }
      }
      const unsigned short* bk =
          &wFk[(((((tap << 3) + c8) << 4) + cog0) << 9) + (lane << 3)];
      const short8 kb0 = *(const short8*)bk;
      const short8 kb1 = *(const short8*)(bk + 512);
#pragma unroll
      for (int f = 0; f < 4; ++f) {
        ak[f][0] = __builtin_amdgcn_mfma_f32_16x16x32_bf16(a[f], kb0,
                                                           ak[f][0], 0, 0, 0);
        ak[f][1] = __builtin_amdgcn_mfma_f32_16x16x32_bf16(a[f], kb1,
                                                           ak[f][1], 0, 0, 0);
      }
      if (vv) {
        const int vt = (kh - 1) * 3 + (kw - 1);
        const unsigned short* bv =
            &wFv[(((((vt << 3) + c8) << 4) + cog0) << 9) + (lane << 3)];
        const short8 vb0 = *(const short8*)bv;
        const short8 vb1 = *(const short8*)(bv + 512);
#pragma unroll
        for (int f = 0; f < 4; ++f) {
          av[f][0] = __builtin_amdgcn_mfma_f32_16x16x32_bf16(a[f], vb0,
                                                             av[f][0], 0, 0, 0);
          av[f][1] = __builtin_amdgcn_mfma_f32_16x16x32_bf16(a[f], vb1,
                                                             av[f][1], 0, 0, 0);
        }
      }
      if (tap == 12) {
        const unsigned short* bq =
            &wFq[(((c8 << 4) + cog0) << 9) + (lane << 3)];
        const short8 qb0 = *(const short8*)bq;
        const short8 qb1 = *(const short8*)(bq + 512);
#pragma unroll
        for (int f = 0; f < 4; ++f) {
          aq[f][0] = __builtin_amdgcn_mfma_f32_16x16x32_bf16(a[f], qb0,
                                                             aq[f][0], 0, 0, 0);
          aq[f][1] = __builtin_amdgcn_mfma_f32_16x16x32_bf16(a[f], qb1,
                                                             aq[f][1], 0, 0, 0);
        }
      }
    }
  }
#pragma unroll
  for (int rr2 = 0; rr2 < 2; ++rr2) {
#pragma unroll
    for (int ch = 0; ch < 2; ++ch) {
      const int f = (rr2 << 1) + ch;
      const int nb = n0 + (wv << 6) + (rr2 << 5) + (ch << 4) + (quad << 2);
#pragma unroll
      for (int ni = 0; ni < 2; ++ni) {
        const int co = co0 + (ni << 4) + l15;
        const int slab = (b << 4) + (co >> 4);
        const int clo = co & 15;
        {
          const float bj = bc[co];
          floatx4 a = aq[f][ni];
          ushort4 pk4;
          pk4.x = f2bf((a[0] + bj) * QSCALE);
          pk4.y = f2bf((a[1] + bj) * QSCALE);
          pk4.z = f2bf((a[2] + bj) * QSCALE);
          pk4.w = f2bf((a[3] + bj) * QSCALE);
          *(ushort4*)&qOut[(slab << 14) + (clo << 10) + nb] = pk4;
        }
        {
          const float bj = bc[512 + co];
          floatx4 a = ak[f][ni];
          ushort4 pk4;
          pk4.x = f2bf(a[0] + bj); pk4.y = f2bf(a[1] + bj);
          pk4.z = f2bf(a[2] + bj); pk4.w = f2bf(a[3] + bj);
          *(ushort4*)&kOut[(slab << 14) + (clo << 10) + nb] = pk4;
        }
        {
          const float bj = bc[256 + co];
          floatx4 a = av[f][ni];
          const int base = (slab << 14) + (clo << 6);
#pragma unroll
          for (int i = 0; i < 4; ++i) {
            const int n = nb + i;
            vOut[base + ((n & 15) << 10) + (n >> 4)] = f2bf(a[i] + bj);
          }
        }
      }
    }
  }
}

// ---------------------------------------------------------------------------
// R17-verified MFMA attention (byte-identical): single-inst exp2, truncating
// bf16 P-store, ones-MFMA row sums, K/V from global, barrier-free, 10.2 KB.
// ---------------------------------------------------------------------------
__global__ __launch_bounds__(256, 4) void attn_mfma_kernel(
    const unsigned short* __restrict__ qg,
    const unsigned short* __restrict__ kg,
    const unsigned short* __restrict__ vg,
    unsigned short* __restrict__ out2) {
  __shared__ __align__(16) unsigned short Pb[4][32][40];  // per-wave P
  const int t    = threadIdx.x;
  const int w    = t >> 6;
  const int lane = t & 63;
  const int slab = blockIdx.x >> 3;
  const int rb   = blockIdx.x & 7;
  const int b = slab >> 4;
  const int h = slab & 15;
  const int l31  = lane & 31;
  const int hl   = lane >> 5;
  const int l15  = lane & 15;
  const int quad = lane >> 4;

  const unsigned short* Kb = kg + (slab << 14);
  const unsigned short* Vb = vg + (slab << 14);

  const int row0 = (rb << 7) + (w << 5);
  const short8 qa =
      *(const short8*)&qg[(slab << 14) + ((row0 + l31) << 4) + (hl << 3)];

  const short onebf = (short)0x3F80;  // bf16 1.0
  const short8 ones = {onebf, onebf, onebf, onebf, onebf, onebf, onebf, onebf};

  floatx4 acco[2] = {}, asum[2] = {};

  for (int kc = 0; kc < 1024; kc += 32) {
    const short8 kb = *(const short8*)&Kb[((kc + l31) << 4) + (hl << 3)];
    floatx16 s = {};
    s = __builtin_amdgcn_mfma_f32_32x32x16_bf16(qa, kb, s, 0, 0, 0);
#pragma unroll
    for (int r = 0; r < 16; ++r) {
      const float e = __builtin_amdgcn_exp2f(s[r]);  // scale pre-folded in Q
      const int row = (r & 3) + ((r >> 2) << 3) + (hl << 2);
      Pb[w][row][l31] = f2bf_trunc(e);
    }
    const short8 vb = *(const short8*)&Vb[(l15 << 10) + kc + (quad << 3)];
#pragma unroll
    for (int tt = 0; tt < 2; ++tt) {
      const short8 pa = *(const short8*)&Pb[w][(tt << 4) + l15][quad << 3];
      acco[tt] =
          __builtin_amdgcn_mfma_f32_16x16x32_bf16(pa, vb, acco[tt], 0, 0, 0);
      asum[tt] =
          __builtin_amdgcn_mfma_f32_16x16x32_bf16(pa, ones, asum[tt], 0, 0, 0);
    }
  }
#pragma unroll
  for (int tt = 0; tt < 2; ++tt) {
#pragma unroll
    for (int r = 0; r < 4; ++r) {
      const int nloc = (tt << 4) + (quad << 2) + r;
      const float val = acco[tt][r] / asum[tt][r];
      const int n = row0 + nloc;
      out2[(((b << 10) + n) << 8) + (h << 4) + l15] = f2bf(val);
    }
  }
}

// ---------------------------------------------------------------------------
// Final linear, MFMA bf16, with one-chunk-ahead B register prefetch.
// ---------------------------------------------------------------------------
__global__ __launch_bounds__(256) void linear_mfma_kernel(
    const unsigned short* __restrict__ inp,  // bf16 [8192][256]
    const unsigned short* __restrict__ wpF,  // fragment order
    void* __restrict__ out, const int* __restrict__ flag) {
  __shared__ unsigned short As[64 * 40];
  const int isf32 = *flag;
  const int t   = threadIdx.x;
  const int m0  = blockIdx.x << 6;
  const int co0 = blockIdx.y << 6;
  const int wv   = t >> 6;
  const int lane = t & 63;
  const int wm = (wv & 1) << 5;
  const int wn = (wv >> 1) << 5;
  const int l15  = lane & 15;
  const int quad = lane >> 4;
  const int cogb = (co0 >> 4) + (wn >> 4);
  const int rowS = t >> 2;
  const int partS = t & 3;

  floatx4 acc[2][2] = {};

  short8 cb0, cb1;
  {
    const unsigned short* wptr = &wpF[(cogb << 9) + (lane << 3)];
    cb0 = *(const short8*)wptr;
    cb1 = *(const short8*)(wptr + 512);
  }
  for (int c8 = 0; c8 < 8; ++c8) {
    const uint4 v = *(const uint4*)&inp[((m0 + rowS) << 8) + (c8 << 5) +
                                        (partS << 3)];
    short8 nb0 = {}, nb1 = {};
    if (c8 + 1 < 8) {
      const unsigned short* wptr =
          &wpF[((((c8 + 1) << 4) + cogb) << 9) + (lane << 3)];
      nb0 = *(const short8*)wptr;
      nb1 = *(const short8*)(wptr + 512);
    }
    __syncthreads();
    *(uint4*)&As[rowS * 40 + (partS << 3)] = v;
    __syncthreads();
    const unsigned short* xs = &As[(wm + l15) * 40 + (quad << 3)];
    const short8 afr0 = *(const short8*)xs;
    const short8 afr1 = *(const short8*)(xs + 16 * 40);
    acc[0][0] = __builtin_amdgcn_mfma_f32_16x16x32_bf16(afr0, cb0,
                                                        acc[0][0], 0, 0, 0);
    acc[0][1] = __builtin_amdgcn_mfma_f32_16x16x32_bf16(afr0, cb1,
                                                        acc[0][1], 0, 0, 0);
    acc[1][0] = __builtin_amdgcn_mfma_f32_16x16x32_bf16(afr1, cb0,
                                                        acc[1][0], 0, 0, 0);
    acc[1][1] = __builtin_amdgcn_mfma_f32_16x16x32_bf16(afr1, cb1,
                                                        acc[1][1], 0, 0, 0);
    cb0 = nb0; cb1 = nb1;
  }
#pragma unroll
  for (int mi = 0; mi < 2; ++mi) {
#pragma unroll
    for (int ni = 0; ni < 2; ++ni) {
      const int co = co0 + wn + (ni << 4) + l15;
      const int mb = m0 + wm + (mi << 4) + (quad << 2);
      floatx4 a = acc[mi][ni];
      if (!isf32) {
        unsigned short* o16 = (unsigned short*)out;
#pragma unroll
        for (int r = 0; r < 4; ++r) o16[(mb + r) * 256 + co] = f2bf(a[r]);
      } else {
        float* o32 = (float*)out;
#pragma unroll
        for (int r = 0; r < 4; ++r) o32[(mb + r) * 256 + co] = a[r];
      }
    }
  }
}

// ---------------------------------------------------------------------------
extern "C" void kernel_launch(void* const* d_in, const int* in_sizes, int n_in,
                              void* d_out, int out_size, void* d_ws,
                              size_t ws_size, hipStream_t stream) {
  const void* x  = d_in[0];
  const void* w3 = d_in[1];
  const void* b3 = d_in[2];
  const void* w5 = d_in[3];
  const void* b5 = d_in[4];
  const void* w7 = d_in[5];
  const void* b7 = d_in[6];
  const void* wp = d_in[7];

  char* p = (char*)d_ws;
  int* flag = (int*)p;                       p += 256;
  unsigned short* xbf = (unsigned short*)p;  p += 4u * 1024 * 1024;
  unsigned short* wF3 = (unsigned short*)p;  p += 131072;
  unsigned short* wF5 = (unsigned short*)p;  p += 1179648;
  unsigned short* wF7 = (unsigned short*)p;  p += 3276800;
  unsigned short* wpF = (unsigned short*)p;  p += 131072;
  float* bc = (float*)p;                     p += 4096;     // [3][256]
  unsigned short* qc  = (unsigned short*)p;  p += 4194304;  // bf16 QK rows
  unsigned short* kT  = (unsigned short*)p;  p += 4194304;  // bf16 QK rows
  unsigned short* vT  = (unsigned short*)p;  p += 4194304;  // bf16 V^T
  unsigned short* o2b = (unsigned short*)p;  p += 4194304;  // bf16 [8192][256]

  prep_kernel<<<1025, 256, 0, stream>>>(x, w3, b3, w5, b5, w7, b7, wp, xbf,
                                        wF3, wF5, wF7, wpF, bc, flag);

  convqkv_kernel<<<256, 256, 0, stream>>>(xbf, wF3, wF5, wF7, bc, qc, vT, kT);

  attn_mfma_kernel<<<1024, 256, 0, stream>>>(qc, kT, vT, o2b);

  dim3 lg(128, 4);
  linear_mfma_kernel<<<lg, 256, 0, stream>>>(o2b, wpF, d_out, flag);
}

// Round 2
// 184.188 us; speedup vs baseline: 1.3060x; 1.3060x over previous
//
#include <hip/hip_runtime.h>
#include <hip/hip_bf16.h>

#define DIM 256
#define HW  1024  // 32*32

typedef __attribute__((ext_vector_type(8))) short short8;
typedef __attribute__((ext_vector_type(4))) float floatx4;
typedef __attribute__((ext_vector_type(16))) float floatx16;
typedef __attribute__((address_space(1))) const unsigned int g_u32;
typedef __attribute__((address_space(3))) unsigned int l_u32;

// softmax scale folded into Q at conv epilogue: 0.25 * log2(e)
#define QSCALE 0.36067376022224085f

__device__ inline unsigned short f2bf(float f) {
  union { float f; unsigned u; } v;
  v.f = f;
  unsigned u = v.u;
  u += 0x7fffu + ((u >> 16) & 1u);
  return (unsigned short)(u >> 16);
}

__device__ inline unsigned short f2bf_trunc(float f) {  // RTZ: 1 VALU inst
  union { float f; unsigned u; } v;
  v.f = f;
  return (unsigned short)(v.u >> 16);
}

__device__ inline float ldin(const void* p, long i, int isf32) {
  if (isf32) return ((const float*)p)[i];
  union { unsigned u; float f; } v;
  v.u = ((unsigned)((const unsigned short*)p)[i]) << 16;
  return v.f;
}

// ---------------------------------------------------------------------------
// R21 fused prep (unchanged).
// wF layout (unchanged): [tap][c8(8)][co16(16)][lane(64)][j(8)],
//   co = co16*16 + (lane&15), ci = c8*32 + (lane>>4)*8 + j.
// ---------------------------------------------------------------------------
__device__ inline int detect_inline(const unsigned short* __restrict__ xr,
                                    int* cnt) {
  if (threadIdx.x == 0) *cnt = 0;
  __syncthreads();
  int local = 0;
  for (int i = threadIdx.x; i < 8192; i += 256) {
    unsigned short u = xr[i];
    if ((u & 0x7F80u) == 0x7F80u) local++;
  }
  if (local) atomicAdd(cnt, local);
  __syncthreads();
  return (*cnt > 0) ? 1 : 0;
}

__device__ inline void frag_repack4(const void* __restrict__ w,
                                    unsigned short* __restrict__ wF, int KK,
                                    int slice, float* __restrict__ Wl,
                                    int isf32) {
  const int t = threadIdx.x;
  const int co16 = slice & 15;
  const int c8   = slice >> 4;
  const int RE = 32 * KK;   // elems per co row (contiguous in source)
  const int RS = RE + 1;    // padded LDS row stride (801 max == 1 mod 32)
  for (int g = 0; g < 4; ++g) {       // 4 co rows per pass
    __syncthreads();                  // previous pass's reads done
    for (int rloc = 0; rloc < 4; ++rloc) {
      const long base =
          ((long)((co16 * 16 + (g << 2) + rloc) * 256 + c8 * 32)) * KK;
      for (int i = t; i < RE; i += 256)
        Wl[rloc * RS + i] = ldin(w, base + i, isf32);
    }
    __syncthreads();
    for (int tap = 0; tap < KK; ++tap) {
      unsigned short* dst = wF + ((((tap << 3) + c8) << 4) + co16) * 512;
      if (t < 128) {
        const int colg = t >> 5;          // local co row 0..3
        const int cis  = t & 31;          // ci-sub 0..31
        const int col  = (g << 2) + colg; // co within co16 tile
        const int lane = ((cis >> 3) << 4) | col;
        const int j    = cis & 7;
        dst[lane * 8 + j] = f2bf(Wl[colg * RS + cis * KK + tap]);
      }
    }
  }
}

__global__ __launch_bounds__(256) void prep_kernel(
    const void* __restrict__ x,  const void* __restrict__ w3,
    const void* __restrict__ b3, const void* __restrict__ w5,
    const void* __restrict__ b5, const void* __restrict__ w7,
    const void* __restrict__ b7, const void* __restrict__ wp,
    unsigned short* __restrict__ xbf,
    unsigned short* __restrict__ wF3, unsigned short* __restrict__ wF5,
    unsigned short* __restrict__ wF7, unsigned short* __restrict__ wpF,
    float* __restrict__ bc, int* __restrict__ flag) {
  __shared__ float Wl[4 * 801];  // 12.8 KB
  __shared__ int cnt;
  const int isf32 = detect_inline((const unsigned short*)x, &cnt);
  const int bid = blockIdx.x;
  const int t = threadIdx.x;
  if (bid < 512) {  // xconv: 16 elems/thread, 4 coalesced rounds
#pragma unroll
    for (int r = 0; r < 4; ++r) {
      const int i = (bid * 1024 + r * 256 + t) * 4;
      if (isf32) {
        const float4 v = *(const float4*)((const float*)x + i);
        ushort4 o;
        o.x = f2bf(v.x); o.y = f2bf(v.y); o.z = f2bf(v.z); o.w = f2bf(v.w);
        *(ushort4*)(xbf + i) = o;
      } else {
        *(ushort4*)(xbf + i) =
            *(const ushort4*)((const unsigned short*)x + i);
      }
    }
  } else if (bid < 640) {
    frag_repack4(w7, wF7, 25, bid - 512, Wl, isf32);
  } else if (bid < 768) {
    frag_repack4(w5, wF5, 9, bid - 640, Wl, isf32);
  } else if (bid < 896) {
    frag_repack4(w3, wF3, 1, bid - 768, Wl, isf32);
  } else if (bid < 1024) {
    frag_repack4(wp, wpF, 1, bid - 896, Wl, isf32);
  } else {  // biases (q=b3, v=b5, k=b7) + publish flag
#pragma unroll
    for (int r = 0; r < 3; ++r) {
      const int i = r * 256 + t;
      const void* src = (i < 256) ? b3 : (i < 512) ? b5 : b7;
      bc[i] = ldin(src, i & 255, isf32);
    }
    if (t == 0) *flag = isf32;
  }
}

// ---------------------------------------------------------------------------
// R23 conv: Tco=32 (R22's verified epilogue/indexing) + R17's DMA-staged B.
//  R22 post-mortem: direct global B reads at 1 wave/SIMD exposed full L2
//  latency per tap (200 taps x ~1.3Kcy = 110us). Fix: stage all 70 B
//  fragments per c8 via global_load_lds, drained once per barrier -- the
//  latency-tolerant structure that ran at 49.7us -- while keeping Tco=32
//  which halves X-LDS bytes/MFMA (0.96 -> 0.61 KB).
//  LDS: Xs 34.6KB + Bs 71.7KB = 106.2KB, 1 block/CU.
// Attention coords (R2/R11-verified): slab=(b<<4)+(co>>4), m=(co&15)*64+(n>>4),
//   d=n&15;  q/k rows: (slab<<14)+((co&15)<<10)+n ;  v (V^T):
//   (slab<<14)+((n&15)<<10)+((co&15)<<6)+(n>>4)
// ---------------------------------------------------------------------------
__global__ __launch_bounds__(256, 1) void convqkv_kernel(
    const unsigned short* __restrict__ xbf,
    const unsigned short* __restrict__ wFq,  // 1 tap
    const unsigned short* __restrict__ wFv,  // 9 taps
    const unsigned short* __restrict__ wFk,  // 25 taps
    const float* __restrict__ bc,            // [3][256] q,v,k
    unsigned short* __restrict__ qOut,
    unsigned short* __restrict__ vOut,
    unsigned short* __restrict__ kOut) {
  constexpr int WC = 36;            // halo cols (32 + 2*2)
  constexpr int CELLS = 12 * WC;    // 12 halo rows = 432 cells
  constexpr int LOADS = CELLS * 4;  // 1728 halo dwordx4 loads
  __shared__ unsigned short Xs[CELLS * 40];  // halo [cell][32ci pad40] 34.6KB
  __shared__ unsigned short Bs[70 * 512];    // B [slot=tap*2+g][lane64][8] 71.7KB
  const int t    = threadIdx.x;
  const int bid  = blockIdx.x;         // 256 = 32 m-groups x 8 co-pairs
  const int cp   = bid & 7;
  const int cog0 = cp << 1;            // first co16 group of the pair
  const int co0  = cp << 5;            // 32 co per block
  const int m0   = (bid >> 3) << 8;    // 256 positions (8 image rows)
  const int b    = m0 >> 10;
  const int n0   = m0 & 1023;
  const int r0   = n0 >> 5;
  const int wv   = t >> 6;
  const int lane = t & 63;
  const int l15  = lane & 15;
  const int quad = lane >> 4;

  floatx4 aq[4][2] = {}, av[4][2] = {}, ak[4][2] = {};

  for (int c8 = 0; c8 < 8; ++c8) {
    uint4 xreg[7];
#pragma unroll
    for (int rr = 0; rr < 7; ++rr) {
      const int id = rr * 256 + t;
      const int cell = id >> 2, part = id & 3;
      const int hr = cell / WC, wc = cell - hr * WC;
      const int xr = r0 + hr - 2, xc = wc - 2;
      const bool ok = (id < LOADS) && ((unsigned)xr < 32u) &&
                      ((unsigned)xc < 32u);
      const int cr = xr < 0 ? 0 : (xr > 31 ? 31 : xr);
      const int cc = xc < 0 ? 0 : (xc > 31 ? 31 : xc);
      uint4 v = *(const uint4*)&xbf[(((b * 32 + cr) * 32 + cc) << 8) +
                                    (c8 << 5) + (part << 3)];
      if (!ok) v = make_uint4(0, 0, 0, 0);
      xreg[rr] = v;
    }
    __syncthreads();
    // stage 70 B fragments (k:25 taps x2, v:9x2, q:1x2) via DMA; drained at
    // the barrier below, so latency hides under the Xs writes.
#pragma unroll
    for (int rr = 0; rr < 18; ++rr) {
      const int slot = (rr << 2) + wv;   // 0..71
      if (slot < 70) {
        const int tap = slot >> 1;       // 0..34: k 0-24, v 25-33, q 34
        const int g   = slot & 1;
        const unsigned short* src;
        if (tap < 25) {
          src = &wFk[((((tap << 3) + c8) << 4) + cog0 + g) * 512];
        } else if (tap < 34) {
          src = &wFv[(((((tap - 25) << 3) + c8) << 4) + cog0 + g) * 512];
        } else {
          src = &wFq[((c8 << 4) + cog0 + g) * 512];
        }
        __builtin_amdgcn_global_load_lds((g_u32*)(src + (lane << 3)),
                                         (l_u32*)&Bs[slot << 9], 16, 0, 0);
      }
    }
#pragma unroll
    for (int rr = 0; rr < 7; ++rr) {
      const int id = rr * 256 + t;
      if (id < LOADS)
        *(uint4*)&Xs[(id >> 2) * 40 + ((id & 3) << 3)] = xreg[rr];
    }
    __syncthreads();

#pragma unroll
    for (int tap = 0; tap < 25; ++tap) {
      const int kh = tap / 5, kw = tap % 5;
      const bool vv = (kh >= 1 && kh <= 3 && kw >= 1 && kw <= 3);
      short8 a[4];
#pragma unroll
      for (int rr2 = 0; rr2 < 2; ++rr2) {
#pragma unroll
        for (int ch = 0; ch < 2; ++ch) {
          const unsigned short* xs =
              &Xs[(((wv << 1) + rr2 + kh) * WC + (ch << 4) + l15 + kw) * 40 +
                  (quad << 3)];
          a[(rr2 << 1) + ch] = *(const short8*)xs;
        }
      }
      const short8 kb0 = *(const short8*)&Bs[((tap << 1) << 9) + (lane << 3)];
      const short8 kb1 =
          *(const short8*)&Bs[(((tap << 1) + 1) << 9) + (lane << 3)];
#pragma unroll
      for (int f = 0; f < 4; ++f) {
        ak[f][0] = __builtin_amdgcn_mfma_f32_16x16x32_bf16(a[f], kb0,
                                                           ak[f][0], 0, 0, 0);
        ak[f][1] = __builtin_amdgcn_mfma_f32_16x16x32_bf16(a[f], kb1,
                                                           ak[f][1], 0, 0, 0);
      }
      if (vv) {
        const int vt = (kh - 1) * 3 + (kw - 1);
        const int vs = (25 + vt) << 1;
        const short8 vb0 = *(const short8*)&Bs[(vs << 9) + (lane << 3)];
        const short8 vb1 = *(const short8*)&Bs[((vs + 1) << 9) + (lane << 3)];
#pragma unroll
        for (int f = 0; f < 4; ++f) {
          av[f][0] = __builtin_amdgcn_mfma_f32_16x16x32_bf16(a[f], vb0,
                                                             av[f][0], 0, 0, 0);
          av[f][1] = __builtin_amdgcn_mfma_f32_16x16x32_bf16(a[f], vb1,
                                                             av[f][1], 0, 0, 0);
        }
      }
      if (tap == 12) {
        const short8 qb0 = *(const short8*)&Bs[(68 << 9) + (lane << 3)];
        const short8 qb1 = *(const short8*)&Bs[(69 << 9) + (lane << 3)];
#pragma unroll
        for (int f = 0; f < 4; ++f) {
          aq[f][0] = __builtin_amdgcn_mfma_f32_16x16x32_bf16(a[f], qb0,
                                                             aq[f][0], 0, 0, 0);
          aq[f][1] = __builtin_amdgcn_mfma_f32_16x16x32_bf16(a[f], qb1,
                                                             aq[f][1], 0, 0, 0);
        }
      }
    }
  }
#pragma unroll
  for (int rr2 = 0; rr2 < 2; ++rr2) {
#pragma unroll
    for (int ch = 0; ch < 2; ++ch) {
      const int f = (rr2 << 1) + ch;
      const int nb = n0 + (wv << 6) + (rr2 << 5) + (ch << 4) + (quad << 2);
#pragma unroll
      for (int ni = 0; ni < 2; ++ni) {
        const int co = co0 + (ni << 4) + l15;
        const int slab = (b << 4) + (co >> 4);
        const int clo = co & 15;
        {
          const float bj = bc[co];
          floatx4 a = aq[f][ni];
          ushort4 pk4;
          pk4.x = f2bf((a[0] + bj) * QSCALE);
          pk4.y = f2bf((a[1] + bj) * QSCALE);
          pk4.z = f2bf((a[2] + bj) * QSCALE);
          pk4.w = f2bf((a[3] + bj) * QSCALE);
          *(ushort4*)&qOut[(slab << 14) + (clo << 10) + nb] = pk4;
        }
        {
          const float bj = bc[512 + co];
          floatx4 a = ak[f][ni];
          ushort4 pk4;
          pk4.x = f2bf(a[0] + bj); pk4.y = f2bf(a[1] + bj);
          pk4.z = f2bf(a[2] + bj); pk4.w = f2bf(a[3] + bj);
          *(ushort4*)&kOut[(slab << 14) + (clo << 10) + nb] = pk4;
        }
        {
          const float bj = bc[256 + co];
          floatx4 a = av[f][ni];
          const int base = (slab << 14) + (clo << 6);
#pragma unroll
          for (int i = 0; i < 4; ++i) {
            const int n = nb + i;
            vOut[base + ((n & 15) << 10) + (n >> 4)] = f2bf(a[i] + bj);
          }
        }
      }
    }
  }
}

// ---------------------------------------------------------------------------
// R17-verified MFMA attention (byte-identical): single-inst exp2, truncating
// bf16 P-store, ones-MFMA row sums, K/V from global, barrier-free, 10.2 KB.
// ---------------------------------------------------------------------------
__global__ __launch_bounds__(256, 4) void attn_mfma_kernel(
    const unsigned short* __restrict__ qg,
    const unsigned short* __restrict__ kg,
    const unsigned short* __restrict__ vg,
    unsigned short* __restrict__ out2) {
  __shared__ __align__(16) unsigned short Pb[4][32][40];  // per-wave P
  const int t    = threadIdx.x;
  const int w    = t >> 6;
  const int lane = t & 63;
  const int slab = blockIdx.x >> 3;
  const int rb   = blockIdx.x & 7;
  const int b = slab >> 4;
  const int h = slab & 15;
  const int l31  = lane & 31;
  const int hl   = lane >> 5;
  const int l15  = lane & 15;
  const int quad = lane >> 4;

  const unsigned short* Kb = kg + (slab << 14);
  const unsigned short* Vb = vg + (slab << 14);

  const int row0 = (rb << 7) + (w << 5);
  const short8 qa =
      *(const short8*)&qg[(slab << 14) + ((row0 + l31) << 4) + (hl << 3)];

  const short onebf = (short)0x3F80;  // bf16 1.0
  const short8 ones = {onebf, onebf, onebf, onebf, onebf, onebf, onebf, onebf};

  floatx4 acco[2] = {}, asum[2] = {};

  for (int kc = 0; kc < 1024; kc += 32) {
    const short8 kb = *(const short8*)&Kb[((kc + l31) << 4) + (hl << 3)];
    floatx16 s = {};
    s = __builtin_amdgcn_mfma_f32_32x32x16_bf16(qa, kb, s, 0, 0, 0);
#pragma unroll
    for (int r = 0; r < 16; ++r) {
      const float e = __builtin_amdgcn_exp2f(s[r]);  // scale pre-folded in Q
      const int row = (r & 3) + ((r >> 2) << 3) + (hl << 2);
      Pb[w][row][l31] = f2bf_trunc(e);
    }
    const short8 vb = *(const short8*)&Vb[(l15 << 10) + kc + (quad << 3)];
#pragma unroll
    for (int tt = 0; tt < 2; ++tt) {
      const short8 pa = *(const short8*)&Pb[w][(tt << 4) + l15][quad << 3];
      acco[tt] =
          __builtin_amdgcn_mfma_f32_16x16x32_bf16(pa, vb, acco[tt], 0, 0, 0);
      asum[tt] =
          __builtin_amdgcn_mfma_f32_16x16x32_bf16(pa, ones, asum[tt], 0, 0, 0);
    }
  }
#pragma unroll
  for (int tt = 0; tt < 2; ++tt) {
#pragma unroll
    for (int r = 0; r < 4; ++r) {
      const int nloc = (tt << 4) + (quad << 2) + r;
      const float val = acco[tt][r] / asum[tt][r];
      const int n = row0 + nloc;
      out2[(((b << 10) + n) << 8) + (h << 4) + l15] = f2bf(val);
    }
  }
}

// ---------------------------------------------------------------------------
// Final linear, MFMA bf16, with one-chunk-ahead B register prefetch.
// ---------------------------------------------------------------------------
__global__ __launch_bounds__(256) void linear_mfma_kernel(
    const unsigned short* __restrict__ inp,  // bf16 [8192][256]
    const unsigned short* __restrict__ wpF,  // fragment order
    void* __restrict__ out, const int* __restrict__ flag) {
  __shared__ unsigned short As[64 * 40];
  const int isf32 = *flag;
  const int t   = threadIdx.x;
  const int m0  = blockIdx.x << 6;
  const int co0 = blockIdx.y << 6;
  const int wv   = t >> 6;
  const int lane = t & 63;
  const int wm = (wv & 1) << 5;
  const int wn = (wv >> 1) << 5;
  const int l15  = lane & 15;
  const int quad = lane >> 4;
  const int cogb = (co0 >> 4) + (wn >> 4);
  const int rowS = t >> 2;
  const int partS = t & 3;

  floatx4 acc[2][2] = {};

  short8 cb0, cb1;
  {
    const unsigned short* wptr = &wpF[(cogb << 9) + (lane << 3)];
    cb0 = *(const short8*)wptr;
    cb1 = *(const short8*)(wptr + 512);
  }
  for (int c8 = 0; c8 < 8; ++c8) {
    const uint4 v = *(const uint4*)&inp[((m0 + rowS) << 8) + (c8 << 5) +
                                        (partS << 3)];
    short8 nb0 = {}, nb1 = {};
    if (c8 + 1 < 8) {
      const unsigned short* wptr =
          &wpF[((((c8 + 1) << 4) + cogb) << 9) + (lane << 3)];
      nb0 = *(const short8*)wptr;
      nb1 = *(const short8*)(wptr + 512);
    }
    __syncthreads();
    *(uint4*)&As[rowS * 40 + (partS << 3)] = v;
    __syncthreads();
    const unsigned short* xs = &As[(wm + l15) * 40 + (quad << 3)];
    const short8 afr0 = *(const short8*)xs;
    const short8 afr1 = *(const short8*)(xs + 16 * 40);
    acc[0][0] = __builtin_amdgcn_mfma_f32_16x16x32_bf16(afr0, cb0,
                                                        acc[0][0], 0, 0, 0);
    acc[0][1] = __builtin_amdgcn_mfma_f32_16x16x32_bf16(afr0, cb1,
                                                        acc[0][1], 0, 0, 0);
    acc[1][0] = __builtin_amdgcn_mfma_f32_16x16x32_bf16(afr1, cb0,
                                                        acc[1][0], 0, 0, 0);
    acc[1][1] = __builtin_amdgcn_mfma_f32_16x16x32_bf16(afr1, cb1,
                                                        acc[1][1], 0, 0, 0);
    cb0 = nb0; cb1 = nb1;
  }
#pragma unroll
  for (int mi = 0; mi < 2; ++mi) {
#pragma unroll
    for (int ni = 0; ni < 2; ++ni) {
      const int co = co0 + wn + (ni << 4) + l15;
      const int mb = m0 + wm + (mi << 4) + (quad << 2);
      floatx4 a = acc[mi][ni];
      if (!isf32) {
        unsigned short* o16 = (unsigned short*)out;
#pragma unroll
        for (int r = 0; r < 4; ++r) o16[(mb + r) * 256 + co] = f2bf(a[r]);
      } else {
        float* o32 = (float*)out;
#pragma unroll
        for (int r = 0; r < 4; ++r) o32[(mb + r) * 256 + co] = a[r];
      }
    }
  }
}

// ---------------------------------------------------------------------------
extern "C" void kernel_launch(void* const* d_in, const int* in_sizes, int n_in,
                              void* d_out, int out_size, void* d_ws,
                              size_t ws_size, hipStream_t stream) {
  const void* x  = d_in[0];
  const void* w3 = d_in[1];
  const void* b3 = d_in[2];
  const void* w5 = d_in[3];
  const void* b5 = d_in[4];
  const void* w7 = d_in[5];
  const void* b7 = d_in[6];
  const void* wp = d_in[7];

  char* p = (char*)d_ws;
  int* flag = (int*)p;                       p += 256;
  unsigned short* xbf = (unsigned short*)p;  p += 4u * 1024 * 1024;
  unsigned short* wF3 = (unsigned short*)p;  p += 131072;
  unsigned short* wF5 = (unsigned short*)p;  p += 1179648;
  unsigned short* wF7 = (unsigned short*)p;  p += 3276800;
  unsigned short* wpF = (unsigned short*)p;  p += 131072;
  float* bc = (float*)p;                     p += 4096;     // [3][256]
  unsigned short* qc  = (unsigned short*)p;  p += 4194304;  // bf16 QK rows
  unsigned short* kT  = (unsigned short*)p;  p += 4194304;  // bf16 QK rows
  unsigned short* vT  = (unsigned short*)p;  p += 4194304;  // bf16 V^T
  unsigned short* o2b = (unsigned short*)p;  p += 4194304;  // bf16 [8192][256]

  prep_kernel<<<1025, 256, 0, stream>>>(x, w3, b3, w5, b5, w7, b7, wp, xbf,
                                        wF3, wF5, wF7, wpF, bc, flag);

  convqkv_kernel<<<256, 256, 0, stream>>>(xbf, wF3, wF5, wF7, bc, qc, vT, kT);

  attn_mfma_kernel<<<1024, 256, 0, stream>>>(qc, kT, vT, o2b);

  dim3 lg(128, 4);
  linear_mfma_kernel<<<lg, 256, 0, stream>>>(o2b, wpF, d_out, flag);
}

// Round 3
// 170.218 us; speedup vs baseline: 1.4132x; 1.0821x over previous
//
#include <hip/hip_runtime.h>
#include <hip/hip_bf16.h>

#define DIM 256
#define HW  1024  // 32*32

typedef __attribute__((ext_vector_type(8))) short short8;
typedef __attribute__((ext_vector_type(4))) float floatx4;
typedef __attribute__((ext_vector_type(16))) float floatx16;
typedef __attribute__((address_space(1))) const unsigned int g_u32;
typedef __attribute__((address_space(3))) unsigned int l_u32;

// softmax scale folded into Q at conv epilogue: 0.25 * log2(e)
#define QSCALE 0.36067376022224085f

__device__ inline unsigned short f2bf(float f) {
  union { float f; unsigned u; } v;
  v.f = f;
  unsigned u = v.u;
  u += 0x7fffu + ((u >> 16) & 1u);
  return (unsigned short)(u >> 16);
}

__device__ inline unsigned short f2bf_trunc(float f) {  // RTZ: 1 VALU inst
  union { float f; unsigned u; } v;
  v.f = f;
  return (unsigned short)(v.u >> 16);
}

__device__ inline float ldin(const void* p, long i, int isf32) {
  if (isf32) return ((const float*)p)[i];
  union { unsigned u; float f; } v;
  v.u = ((unsigned)((const unsigned short*)p)[i]) << 16;
  return v.f;
}

// ---------------------------------------------------------------------------
// R21 fused prep (unchanged).
// wF layout (unchanged): [tap][c8(8)][co16(16)][lane(64)][j(8)],
//   co = co16*16 + (lane&15), ci = c8*32 + (lane>>4)*8 + j.
// ---------------------------------------------------------------------------
__device__ inline int detect_inline(const unsigned short* __restrict__ xr,
                                    int* cnt) {
  if (threadIdx.x == 0) *cnt = 0;
  __syncthreads();
  int local = 0;
  for (int i = threadIdx.x; i < 8192; i += 256) {
    unsigned short u = xr[i];
    if ((u & 0x7F80u) == 0x7F80u) local++;
  }
  if (local) atomicAdd(cnt, local);
  __syncthreads();
  return (*cnt > 0) ? 1 : 0;
}

__device__ inline void frag_repack4(const void* __restrict__ w,
                                    unsigned short* __restrict__ wF, int KK,
                                    int slice, float* __restrict__ Wl,
                                    int isf32) {
  const int t = threadIdx.x;
  const int co16 = slice & 15;
  const int c8   = slice >> 4;
  const int RE = 32 * KK;   // elems per co row (contiguous in source)
  const int RS = RE + 1;    // padded LDS row stride (801 max == 1 mod 32)
  for (int g = 0; g < 4; ++g) {       // 4 co rows per pass
    __syncthreads();                  // previous pass's reads done
    for (int rloc = 0; rloc < 4; ++rloc) {
      const long base =
          ((long)((co16 * 16 + (g << 2) + rloc) * 256 + c8 * 32)) * KK;
      for (int i = t; i < RE; i += 256)
        Wl[rloc * RS + i] = ldin(w, base + i, isf32);
    }
    __syncthreads();
    for (int tap = 0; tap < KK; ++tap) {
      unsigned short* dst = wF + ((((tap << 3) + c8) << 4) + co16) * 512;
      if (t < 128) {
        const int colg = t >> 5;          // local co row 0..3
        const int cis  = t & 31;          // ci-sub 0..31
        const int col  = (g << 2) + colg; // co within co16 tile
        const int lane = ((cis >> 3) << 4) | col;
        const int j    = cis & 7;
        dst[lane * 8 + j] = f2bf(Wl[colg * RS + cis * KK + tap]);
      }
    }
  }
}

__global__ __launch_bounds__(256) void prep_kernel(
    const void* __restrict__ x,  const void* __restrict__ w3,
    const void* __restrict__ b3, const void* __restrict__ w5,
    const void* __restrict__ b5, const void* __restrict__ w7,
    const void* __restrict__ b7, const void* __restrict__ wp,
    unsigned short* __restrict__ xbf,
    unsigned short* __restrict__ wF3, unsigned short* __restrict__ wF5,
    unsigned short* __restrict__ wF7, unsigned short* __restrict__ wpF,
    float* __restrict__ bc, int* __restrict__ flag) {
  __shared__ float Wl[4 * 801];  // 12.8 KB
  __shared__ int cnt;
  const int isf32 = detect_inline((const unsigned short*)x, &cnt);
  const int bid = blockIdx.x;
  const int t = threadIdx.x;
  if (bid < 512) {  // xconv: 16 elems/thread, 4 coalesced rounds
#pragma unroll
    for (int r = 0; r < 4; ++r) {
      const int i = (bid * 1024 + r * 256 + t) * 4;
      if (isf32) {
        const float4 v = *(const float4*)((const float*)x + i);
        ushort4 o;
        o.x = f2bf(v.x); o.y = f2bf(v.y); o.z = f2bf(v.z); o.w = f2bf(v.w);
        *(ushort4*)(xbf + i) = o;
      } else {
        *(ushort4*)(xbf + i) =
            *(const ushort4*)((const unsigned short*)x + i);
      }
    }
  } else if (bid < 640) {
    frag_repack4(w7, wF7, 25, bid - 512, Wl, isf32);
  } else if (bid < 768) {
    frag_repack4(w5, wF5, 9, bid - 640, Wl, isf32);
  } else if (bid < 896) {
    frag_repack4(w3, wF3, 1, bid - 768, Wl, isf32);
  } else if (bid < 1024) {
    frag_repack4(wp, wpF, 1, bid - 896, Wl, isf32);
  } else {  // biases (q=b3, v=b5, k=b7) + publish flag
#pragma unroll
    for (int r = 0; r < 3; ++r) {
      const int i = r * 256 + t;
      const void* src = (i < 256) ? b3 : (i < 512) ? b5 : b7;
      bc[i] = ldin(src, i & 255, isf32);
    }
    if (t == 0) *flag = isf32;
  }
}

// ---------------------------------------------------------------------------
// R24 conv: R17 shape restored (Tco=16, 512 blocks, 2 blocks/CU -- the only
// occupancy regime that worked: R22/R23's Tco=32 forces 1 wave/SIMD, all
// latency exposed). NEW: kw-outer X-fragment register reuse. The a-frag for
// (rr2,kh) depends only on row=rr2+kh, so per kw we load the 12 distinct
// frags (6 rows x 2 ch) ONCE into registers and run all 5 kh against them:
// 60 instead of 100 b128 X-reads per wave per c8 (1.67x less traffic on the
// LDS port, which was ~95% busy: 8 waves x 135KB/c8 vs ~85-100 B/cy).
// Staging, layouts, sync, epilogue byte-identical to the 49.7us R17 kernel.
// Attention coords (R2/R11-verified): slab=(b<<4)+(co>>4), m=(co&15)*64+(n>>4),
//   d=n&15;  q/k rows: (slab<<14)+((co&15)<<10)+n ;  v (V^T):
//   (slab<<14)+((n&15)<<10)+((co&15)<<6)+(n>>4)
// ---------------------------------------------------------------------------
__global__ __launch_bounds__(256, 2) void convqkv_kernel(
    const unsigned short* __restrict__ xbf,
    const unsigned short* __restrict__ wFq,  // 1 tap
    const unsigned short* __restrict__ wFv,  // 9 taps
    const unsigned short* __restrict__ wFk,  // 25 taps
    const float* __restrict__ bc,            // [3][256] q,v,k
    unsigned short* __restrict__ qOut,
    unsigned short* __restrict__ vOut,
    unsigned short* __restrict__ kOut) {
  constexpr int WC = 36;            // halo cols (32 + 2*2)
  constexpr int CELLS = 12 * WC;    // 12 halo rows = 432 cells
  constexpr int LOADS = CELLS * 4;  // 1728 halo dwordx4 loads
  __shared__ unsigned short Xs[CELLS * 40];  // halo [cell][32ci pad40] 34.6KB
  __shared__ unsigned short Bs[36 * 512];    // B [tap35+1][lane64][8]  36.9KB
  const int t    = threadIdx.x;
  const int bid  = blockIdx.x;
  const int cog0 = bid & 15;
  const int co0  = cog0 << 4;
  const int m0   = (bid >> 4) << 8;    // 256 positions (8 image rows)
  const int b    = m0 >> 10;
  const int n0   = m0 & 1023;
  const int r0   = n0 >> 5;
  const int wv   = t >> 6;
  const int lane = t & 63;
  const int l15  = lane & 15;
  const int quad = lane >> 4;

  floatx4 aq[4] = {}, av[4] = {}, ak[4] = {};

  for (int c8 = 0; c8 < 8; ++c8) {
    uint4 xreg[7];
#pragma unroll
    for (int rr = 0; rr < 7; ++rr) {
      const int id = rr * 256 + t;
      const int cell = id >> 2, part = id & 3;
      const int hr = cell / WC, wc = cell - hr * WC;
      const int xr = r0 + hr - 2, xc = wc - 2;
      const bool ok = (id < LOADS) && ((unsigned)xr < 32u) &&
                      ((unsigned)xc < 32u);
      const int cr = xr < 0 ? 0 : (xr > 31 ? 31 : xr);
      const int cc = xc < 0 ? 0 : (xc > 31 ? 31 : xc);
      uint4 v = *(const uint4*)&xbf[(((b * 32 + cr) * 32 + cc) << 8) +
                                    (c8 << 5) + (part << 3)];
      if (!ok) v = make_uint4(0, 0, 0, 0);
      xreg[rr] = v;
    }
    __syncthreads();
#pragma unroll
    for (int rr = 0; rr < 9; ++rr) {
      const int tap = (rr << 2) + wv;
      if (tap < 35) {
        const unsigned short* src;
        if (tap < 25) {
          src = &wFk[((((tap << 3) + c8) << 4) + cog0) * 512];
        } else if (tap < 34) {
          src = &wFv[(((((tap - 25) << 3) + c8) << 4) + cog0) * 512];
        } else {
          src = &wFq[((c8 << 4) + cog0) * 512];
        }
        __builtin_amdgcn_global_load_lds((g_u32*)(src + (lane << 3)),
                                         (l_u32*)&Bs[tap << 9], 16, 0, 0);
      }
    }
#pragma unroll
    for (int rr = 0; rr < 7; ++rr) {
      const int id = rr * 256 + t;
      if (id < LOADS)
        *(uint4*)&Xs[(id >> 2) * 40 + ((id & 3) << 3)] = xreg[rr];
    }
    __syncthreads();

#pragma unroll
    for (int kw = 0; kw < 5; ++kw) {
      // 12 distinct X frags for this kw: rows (wv*2 + 0..5), ch 0..1.
      short8 a[6][2];
#pragma unroll
      for (int ri = 0; ri < 6; ++ri) {
#pragma unroll
        for (int ch = 0; ch < 2; ++ch) {
          const unsigned short* xs =
              &Xs[(((wv << 1) + ri) * WC + (ch << 4) + l15 + kw) * 40 +
                  (quad << 3)];
          a[ri][ch] = *(const short8*)xs;
        }
      }
#pragma unroll
      for (int kh = 0; kh < 5; ++kh) {
        const int tap = kh * 5 + kw;
        const short8 kb = *(const short8*)&Bs[(tap << 9) + (lane << 3)];
#pragma unroll
        for (int rr2 = 0; rr2 < 2; ++rr2) {
#pragma unroll
          for (int ch = 0; ch < 2; ++ch) {
            const int f = (rr2 << 1) + ch;
            ak[f] = __builtin_amdgcn_mfma_f32_16x16x32_bf16(
                a[rr2 + kh][ch], kb, ak[f], 0, 0, 0);
          }
        }
        if (kh >= 1 && kh <= 3 && kw >= 1 && kw <= 3) {
          const int vt = (kh - 1) * 3 + (kw - 1);
          const short8 vb =
              *(const short8*)&Bs[((25 + vt) << 9) + (lane << 3)];
#pragma unroll
          for (int rr2 = 0; rr2 < 2; ++rr2) {
#pragma unroll
            for (int ch = 0; ch < 2; ++ch) {
              const int f = (rr2 << 1) + ch;
              av[f] = __builtin_amdgcn_mfma_f32_16x16x32_bf16(
                  a[rr2 + kh][ch], vb, av[f], 0, 0, 0);
            }
          }
        }
        if (tap == 12) {
          const short8 qb = *(const short8*)&Bs[(34 << 9) + (lane << 3)];
#pragma unroll
          for (int rr2 = 0; rr2 < 2; ++rr2) {
#pragma unroll
            for (int ch = 0; ch < 2; ++ch) {
              const int f = (rr2 << 1) + ch;
              aq[f] = __builtin_amdgcn_mfma_f32_16x16x32_bf16(
                  a[rr2 + kh][ch], qb, aq[f], 0, 0, 0);
            }
          }
        }
      }
    }
  }
#pragma unroll
  for (int rr2 = 0; rr2 < 2; ++rr2) {
#pragma unroll
    for (int ch = 0; ch < 2; ++ch) {
      const int f = (rr2 << 1) + ch;
      const int co = co0 + l15;
      const int slab = (b << 4) + (co >> 4);
      const int clo = co & 15;
      const int nb = n0 + (wv << 6) + (rr2 << 5) + (ch << 4) + (quad << 2);
      {
        const float bj = bc[co];
        floatx4 a = aq[f];
        ushort4 pk4;
        pk4.x = f2bf((a[0] + bj) * QSCALE);
        pk4.y = f2bf((a[1] + bj) * QSCALE);
        pk4.z = f2bf((a[2] + bj) * QSCALE);
        pk4.w = f2bf((a[3] + bj) * QSCALE);
        *(ushort4*)&qOut[(slab << 14) + (clo << 10) + nb] = pk4;
      }
      {
        const float bj = bc[512 + co];
        floatx4 a = ak[f];
        ushort4 pk4;
        pk4.x = f2bf(a[0] + bj); pk4.y = f2bf(a[1] + bj);
        pk4.z = f2bf(a[2] + bj); pk4.w = f2bf(a[3] + bj);
        *(ushort4*)&kOut[(slab << 14) + (clo << 10) + nb] = pk4;
      }
      {
        const float bj = bc[256 + co];
        floatx4 a = av[f];
        const int base = (slab << 14) + (clo << 6);
#pragma unroll
        for (int i = 0; i < 4; ++i) {
          const int n = nb + i;
          vOut[base + ((n & 15) << 10) + (n >> 4)] = f2bf(a[i] + bj);
        }
      }
    }
  }
}

// ---------------------------------------------------------------------------
// R24 attn: swapped QK^T (mfma(kb,qa)) so each lane holds P[q=l31][k] with
// 4 CONSECUTIVE k per register group -> P-store becomes 8 v_cvt_pk_bf16_f32
// + 4 ds_write_b64 per iter (was 16 f2bf + 16 scalar ds_write_b16).
// Pb layout (P[q][k], stride 40) and the PV read side are unchanged.
// ---------------------------------------------------------------------------
__global__ __launch_bounds__(256, 4) void attn_mfma_kernel(
    const unsigned short* __restrict__ qg,
    const unsigned short* __restrict__ kg,
    const unsigned short* __restrict__ vg,
    unsigned short* __restrict__ out2) {
  __shared__ __align__(16) unsigned short Pb[4][32][40];  // per-wave P
  const int t    = threadIdx.x;
  const int w    = t >> 6;
  const int lane = t & 63;
  const int slab = blockIdx.x >> 3;
  const int rb   = blockIdx.x & 7;
  const int b = slab >> 4;
  const int h = slab & 15;
  const int l31  = lane & 31;
  const int hl   = lane >> 5;
  const int l15  = lane & 15;
  const int quad = lane >> 4;

  const unsigned short* Kb = kg + (slab << 14);
  const unsigned short* Vb = vg + (slab << 14);

  const int row0 = (rb << 7) + (w << 5);
  const short8 qa =
      *(const short8*)&qg[(slab << 14) + ((row0 + l31) << 4) + (hl << 3)];

  const short onebf = (short)0x3F80;  // bf16 1.0
  const short8 ones = {onebf, onebf, onebf, onebf, onebf, onebf, onebf, onebf};

  floatx4 acco[2] = {}, asum[2] = {};

  for (int kc = 0; kc < 1024; kc += 32) {
    const short8 kb = *(const short8*)&Kb[((kc + l31) << 4) + (hl << 3)];
    floatx16 s = {};
    // swapped: D[m=k][n=q] -> lane holds q=l31, k = 8g + 4hl + j for s[4g+j]
    s = __builtin_amdgcn_mfma_f32_32x32x16_bf16(kb, qa, s, 0, 0, 0);
#pragma unroll
    for (int g = 0; g < 4; ++g) {
      const float e0 = __builtin_amdgcn_exp2f(s[(g << 2) + 0]);
      const float e1 = __builtin_amdgcn_exp2f(s[(g << 2) + 1]);
      const float e2 = __builtin_amdgcn_exp2f(s[(g << 2) + 2]);
      const float e3 = __builtin_amdgcn_exp2f(s[(g << 2) + 3]);
      unsigned lo, hi;
      asm("v_cvt_pk_bf16_f32 %0, %1, %2" : "=v"(lo) : "v"(e0), "v"(e1));
      asm("v_cvt_pk_bf16_f32 %0, %1, %2" : "=v"(hi) : "v"(e2), "v"(e3));
      uint2 pk; pk.x = lo; pk.y = hi;
      *(uint2*)&Pb[w][l31][(g << 3) + (hl << 2)] = pk;  // k=8g+4hl..+3
    }
    const short8 vb = *(const short8*)&Vb[(l15 << 10) + kc + (quad << 3)];
#pragma unroll
    for (int tt = 0; tt < 2; ++tt) {
      const short8 pa = *(const short8*)&Pb[w][(tt << 4) + l15][quad << 3];
      acco[tt] =
          __builtin_amdgcn_mfma_f32_16x16x32_bf16(pa, vb, acco[tt], 0, 0, 0);
      asum[tt] =
          __builtin_amdgcn_mfma_f32_16x16x32_bf16(pa, ones, asum[tt], 0, 0, 0);
    }
  }
#pragma unroll
  for (int tt = 0; tt < 2; ++tt) {
#pragma unroll
    for (int r = 0; r < 4; ++r) {
      const int nloc = (tt << 4) + (quad << 2) + r;
      const float val = acco[tt][r] / asum[tt][r];
      const int n = row0 + nloc;
      out2[(((b << 10) + n) << 8) + (h << 4) + l15] = f2bf(val);
    }
  }
}

// ---------------------------------------------------------------------------
// Final linear, MFMA bf16, with one-chunk-ahead B register prefetch.
// ---------------------------------------------------------------------------
__global__ __launch_bounds__(256) void linear_mfma_kernel(
    const unsigned short* __restrict__ inp,  // bf16 [8192][256]
    const unsigned short* __restrict__ wpF,  // fragment order
    void* __restrict__ out, const int* __restrict__ flag) {
  __shared__ unsigned short As[64 * 40];
  const int isf32 = *flag;
  const int t   = threadIdx.x;
  const int m0  = blockIdx.x << 6;
  const int co0 = blockIdx.y << 6;
  const int wv   = t >> 6;
  const int lane = t & 63;
  const int wm = (wv & 1) << 5;
  const int wn = (wv >> 1) << 5;
  const int l15  = lane & 15;
  const int quad = lane >> 4;
  const int cogb = (co0 >> 4) + (wn >> 4);
  const int rowS = t >> 2;
  const int partS = t & 3;

  floatx4 acc[2][2] = {};

  short8 cb0, cb1;
  {
    const unsigned short* wptr = &wpF[(cogb << 9) + (lane << 3)];
    cb0 = *(const short8*)wptr;
    cb1 = *(const short8*)(wptr + 512);
  }
  for (int c8 = 0; c8 < 8; ++c8) {
    const uint4 v = *(const uint4*)&inp[((m0 + rowS) << 8) + (c8 << 5) +
                                        (partS << 3)];
    short8 nb0 = {}, nb1 = {};
    if (c8 + 1 < 8) {
      const unsigned short* wptr =
          &wpF[((((c8 + 1) << 4) + cogb) << 9) + (lane << 3)];
      nb0 = *(const short8*)wptr;
      nb1 = *(const short8*)(wptr + 512);
    }
    __syncthreads();
    *(uint4*)&As[rowS * 40 + (partS << 3)] = v;
    __syncthreads();
    const unsigned short* xs = &As[(wm + l15) * 40 + (quad << 3)];
    const short8 afr0 = *(const short8*)xs;
    const short8 afr1 = *(const short8*)(xs + 16 * 40);
    acc[0][0] = __builtin_amdgcn_mfma_f32_16x16x32_bf16(afr0, cb0,
                                                        acc[0][0], 0, 0, 0);
    acc[0][1] = __builtin_amdgcn_mfma_f32_16x16x32_bf16(afr0, cb1,
                                                        acc[0][1], 0, 0, 0);
    acc[1][0] = __builtin_amdgcn_mfma_f32_16x16x32_bf16(afr1, cb0,
                                                        acc[1][0], 0, 0, 0);
    acc[1][1] = __builtin_amdgcn_mfma_f32_16x16x32_bf16(afr1, cb1,
                                                        acc[1][1], 0, 0, 0);
    cb0 = nb0; cb1 = nb1;
  }
#pragma unroll
  for (int mi = 0; mi < 2; ++mi) {
#pragma unroll
    for (int ni = 0; ni < 2; ++ni) {
      const int co = co0 + wn + (ni << 4) + l15;
      const int mb = m0 + wm + (mi << 4) + (quad << 2);
      floatx4 a = acc[mi][ni];
      if (!isf32) {
        unsigned short* o16 = (unsigned short*)out;
#pragma unroll
        for (int r = 0; r < 4; ++r) o16[(mb + r) * 256 + co] = f2bf(a[r]);
      } else {
        float* o32 = (float*)out;
#pragma unroll
        for (int r = 0; r < 4; ++r) o32[(mb + r) * 256 + co] = a[r];
      }
    }
  }
}

// ---------------------------------------------------------------------------
extern "C" void kernel_launch(void* const* d_in, const int* in_sizes, int n_in,
                              void* d_out, int out_size, void* d_ws,
                              size_t ws_size, hipStream_t stream) {
  const void* x  = d_in[0];
  const void* w3 = d_in[1];
  const void* b3 = d_in[2];
  const void* w5 = d_in[3];
  const void* b5 = d_in[4];
  const void* w7 = d_in[5];
  const void* b7 = d_in[6];
  const void* wp = d_in[7];

  char* p = (char*)d_ws;
  int* flag = (int*)p;                       p += 256;
  unsigned short* xbf = (unsigned short*)p;  p += 4u * 1024 * 1024;
  unsigned short* wF3 = (unsigned short*)p;  p += 131072;
  unsigned short* wF5 = (unsigned short*)p;  p += 1179648;
  unsigned short* wF7 = (unsigned short*)p;  p += 3276800;
  unsigned short* wpF = (unsigned short*)p;  p += 131072;
  float* bc = (float*)p;                     p += 4096;     // [3][256]
  unsigned short* qc  = (unsigned short*)p;  p += 4194304;  // bf16 QK rows
  unsigned short* kT  = (unsigned short*)p;  p += 4194304;  // bf16 QK rows
  unsigned short* vT  = (unsigned short*)p;  p += 4194304;  // bf16 V^T
  unsigned short* o2b = (unsigned short*)p;  p += 4194304;  // bf16 [8192][256]

  prep_kernel<<<1025, 256, 0, stream>>>(x, w3, b3, w5, b5, w7, b7, wp, xbf,
                                        wF3, wF5, wF7, wpF, bc, flag);

  convqkv_kernel<<<512, 256, 0, stream>>>(xbf, wF3, wF5, wF7, bc, qc, vT, kT);

  attn_mfma_kernel<<<1024, 256, 0, stream>>>(qc, kT, vT, o2b);

  dim3 lg(128, 4);
  linear_mfma_kernel<<<lg, 256, 0, stream>>>(o2b, wpF, d_out, flag);
}